// Round 4
// baseline (24.213 us; speedup 1.0000x reference)
//
#include <hip/hip_runtime.h>

// CoupledFourierSystem: out[t][j] = b[j] + sum_d W[j][d] * sum_{h,c} A[d][h][c]*cos(w[d][h][c]*s_t + phi[d][h][c])
// S=32768, DIM=64, H=16 (HC=32)
//
// Geometry: 1024 blocks x 256 threads (4 waves). Waves pair up: pair = wid>>1
// owns 16 time points; the two waves of a pair each compute 16 of the 32
// harmonics (halves). 4096 waves total -> 4 waves/SIMD resident (vs 2 before).
// Matvec in f16 via v_dot2_f32_f16 (W as half2 -> 32 VGPRs, half the issue).

typedef float  f32x2  __attribute__((ext_vector_type(2)));
typedef _Float16 h16x2 __attribute__((ext_vector_type(2)));
typedef _Float16 h16x8 __attribute__((ext_vector_type(8)));

constexpr int S_PTS = 32768;
constexpr int DIM   = 64;
constexpr int HC    = 32;   // H*2
constexpr int TPP   = 16;   // time points per wave-pair
constexpr float INV_2PI = 0.15915494309189535f;

static __device__ __forceinline__ h16x2 pack_h2(float x, float y) {
    // cvt_pkrtz returns __fp16 ext_vector_type(2); bit-identical to h16x2
    return __builtin_bit_cast(h16x2, __builtin_amdgcn_cvt_pkrtz(x, y));
}

static __device__ __forceinline__ float dot2(h16x2 a, h16x2 b, float c) {
#if __has_builtin(__builtin_amdgcn_fdot2)
    return __builtin_amdgcn_fdot2(a, b, c, false);
#else
    return c + (float)a[0] * (float)b[0] + (float)a[1] * (float)b[1];
#endif
}

__global__ __launch_bounds__(256, 4)
void fourier_fused(const float* __restrict__ s,
                   const float* __restrict__ A,
                   const float* __restrict__ phi,
                   const float* __restrict__ w,
                   const float* __restrict__ Wm,
                   const float* __restrict__ b,
                   float* __restrict__ out)
{
    __shared__ float  pf[2][2][TPP][DIM];      // [pair][half][t][d] partials, 16 KB
    __shared__ h16x2  ph[2][TPP][DIM / 2];     // packed summed rows, 4 KB

    const int lane = threadIdx.x & 63;
    const int wid  = threadIdx.x >> 6;
    const int pair = wid >> 1;
    const int half = wid & 1;
    const int t0   = blockIdx.x * (2 * TPP) + pair * TPP;

    // ---- params: this half's 16 harmonics for d = lane, scaled to revolutions ----
    f32x2 a2[8], w2[8], p2[8];
    {
        const float4* A4 = reinterpret_cast<const float4*>(A   + lane * HC + half * 16);
        const float4* P4 = reinterpret_cast<const float4*>(phi + lane * HC + half * 16);
        const float4* W4 = reinterpret_cast<const float4*>(w   + lane * HC + half * 16);
        #pragma unroll
        for (int q = 0; q < 4; ++q) {
            float4 av = A4[q], pv = P4[q], wv = W4[q];
            a2[2*q+0] = f32x2{av.x, av.y};
            a2[2*q+1] = f32x2{av.z, av.w};
            p2[2*q+0] = f32x2{pv.x, pv.y} * INV_2PI;
            p2[2*q+1] = f32x2{pv.z, pv.w} * INV_2PI;
            w2[2*q+0] = f32x2{wv.x, wv.y} * INV_2PI;
            w2[2*q+1] = f32x2{wv.z, wv.w} * INV_2PI;
        }
    }

    // lanes 0..15 hold the pair's 16 time values
    const float sv = s[t0 + (lane & (TPP - 1))];

    // ---- phase A: 16 partial Fourier sums, written straight to LDS ----
    #pragma unroll
    for (int k = 0; k < TPP; ++k) {
        const float st = __uint_as_float(__builtin_amdgcn_readlane(__float_as_uint(sv), k));
        const f32x2 st2 = {st, st};
        f32x2 ac0 = {0.f, 0.f}, ac1 = {0.f, 0.f};
        #pragma unroll
        for (int i = 0; i < 8; i += 2) {
            f32x2 phs0 = w2[i+0] * st2 + p2[i+0];   // v_pk_fma_f32 candidates
            f32x2 phs1 = w2[i+1] * st2 + p2[i+1];
            f32x2 c0 = { __builtin_amdgcn_cosf(phs0.x), __builtin_amdgcn_cosf(phs0.y) };
            f32x2 c1 = { __builtin_amdgcn_cosf(phs1.x), __builtin_amdgcn_cosf(phs1.y) };
            ac0 = a2[i+0] * c0 + ac0;
            ac1 = a2[i+1] * c1 + ac1;
        }
        const f32x2 acs = ac0 + ac1;
        pf[pair][half][k][lane] = acs.x + acs.y;   // bank = lane%32, 2-way (free)
    }
    __syncthreads();

    // ---- W row as half2 pairs (lane = j) + bias; loaded after phase A ----
    h16x2 wr[DIM / 2];
    {
        const float4* Wr4 = reinterpret_cast<const float4*>(Wm + lane * DIM);
        #pragma unroll
        for (int q = 0; q < DIM / 4; ++q) {
            float4 v = Wr4[q];
            wr[2*q+0] = pack_h2(v.x, v.y);
            wr[2*q+1] = pack_h2(v.z, v.w);
        }
    }
    const float bj = b[lane];

    // ---- pack: sum halves + f32->f16x2; this wave packs its 8 matvec rows ----
    {
        const int p  = lane & 31;    // d-pair index
        const int rs = lane >> 5;    // row sub-offset
        #pragma unroll
        for (int j = 0; j < 4; ++j) {
            const int r = half * 8 + 2 * j + rs;
            f32x2 vA = *reinterpret_cast<const f32x2*>(&pf[pair][0][r][2 * p]);
            f32x2 vB = *reinterpret_cast<const f32x2*>(&pf[pair][1][r][2 * p]);
            f32x2 v  = vA + vB;
            ph[pair][r][p] = pack_h2(v.x, v.y);
        }
    }
    __syncthreads();

    // ---- matvec: 8 rows per wave, f16 dot2, broadcast LDS reads ----
    #pragma unroll
    for (int r0 = 0; r0 < 8; ++r0) {
        const int r = half * 8 + r0;
        const h16x8* row = reinterpret_cast<const h16x8*>(&ph[pair][r][0]); // 8 x 16B
        float o0 = bj, o1 = 0.f, o2 = 0.f, o3 = 0.f;
        #pragma unroll
        for (int q = 0; q < 8; ++q) {
            h16x8 pv = row[q];
            h16x2 q0 = __builtin_shufflevector(pv, pv, 0, 1);
            h16x2 q1 = __builtin_shufflevector(pv, pv, 2, 3);
            h16x2 q2 = __builtin_shufflevector(pv, pv, 4, 5);
            h16x2 q3 = __builtin_shufflevector(pv, pv, 6, 7);
            o0 = dot2(q0, wr[4*q+0], o0);
            o1 = dot2(q1, wr[4*q+1], o1);
            o2 = dot2(q2, wr[4*q+2], o2);
            o3 = dot2(q3, wr[4*q+3], o3);
        }
        out[(t0 + r) * DIM + lane] = (o0 + o1) + (o2 + o3);
    }
}

extern "C" void kernel_launch(void* const* d_in, const int* in_sizes, int n_in,
                              void* d_out, int out_size, void* d_ws, size_t ws_size,
                              hipStream_t stream) {
    const float* s   = (const float*)d_in[0];
    // d_in[1] is x — unused by the forward pass
    const float* A   = (const float*)d_in[2];
    const float* phi = (const float*)d_in[3];
    const float* w   = (const float*)d_in[4];
    const float* Wm  = (const float*)d_in[5];
    const float* b   = (const float*)d_in[6];
    float* out = (float*)d_out;

    dim3 grid(S_PTS / (2 * TPP));   // 1024 blocks x (2 pairs x 16 t) = 32768
    dim3 block(256);
    hipLaunchKernelGGL(fourier_fused, grid, block, 0, stream,
                       s, A, phi, w, Wm, b, out);
}